// Round 8
// baseline (179.321 us; speedup 1.0000x reference)
//
#include <hip/hip_runtime.h>
#include <math.h>

// Problem constants (from reference)
#define NA 3
#define NC 80
#define CH 85              // NC+5
#define NB 16
#define HH 52
#define WW 52
#define HW 2704            // HH*WW
#define HWF4 676           // HW/4
#define NT 256             // num targets
#define NCELLS (NB*NA*HW)  // 129792
#define NBMW 4056          // bitmap words = ceil(NCELLS/32)
#define STRIDE_F 8.0f      // 416/52
#define IGN_THR 0.5f

// R12 post-mortem: wave-pipeline regressed (67us) -- low residency (513
// blocks) + per-lane strided addressing + compiler likely sank the
// prefetch. Root cause across ALL rounds: memory-issue duty cycle ~20%
// (9 loads then a long dead window) => 1.3TB/s ceiling. __syncthreads
// drains vmcnt(0) so no block-tile variant could ever pipeline. R13:
// the guide's verified raw-barrier pattern (8-phase GEMM template):
// __builtin_amdgcn_s_barrier() + lgkmcnt(0)-only waits -> next tile's 9
// float4 loads are issued between the two barriers and stay OUTSTANDING
// across the whole LDS round-trip + store phase. 512 persistent dense
// blocks pull tiles from an atomic work queue (depth ~2.44 -> pipeline);
// tail runs on blocks 1..67 after their FIRST stolen tile (~15us in,
// prep flag long set -> no spin), then they rejoin the queue.
#define TF4 26
#define NF4 2210           // CH * TF4 f4-elements per tile
#define LSTR 105
#define LDSW 8945          // SW(84,103)+1 words = 35.8 KB -> 4 blk/CU
#define NDENSE 1248        // 26 chunks * 48 (B*A)
#define NDB 512            // persistent dense blocks (bids 1..512)
#define NEPI 67            // of those, bids 1..67 also run the tail
#define GRID (1 + NDB)     // 513 done-counter participants

#define SW(c, l) ((c) * LSTR + (l) + ((c) >> 2))

__device__ __forceinline__ float sigm(float z) { return 1.0f / (1.0f + expf(-z)); }
// -log(sigmoid(z)) = log1p(exp(-z));  -log(1-sigmoid(z)) = log1p(exp(z))
__device__ __forceinline__ float splus(float z) { return log1pf(expf(z)); }

// ws layout (bytes):
//   0    : float acc[16]  acc[0]=dense noobj, acc[1]=obj xywh+conf,
//                         acc[2]=cls, acc[3]=zero-cell correction
//   64   : int cnts[8]    {wcount, zcount, unused, done, prep_flag, workq}
//   128  : int   wofs[256]
//   1152 : float wtx[256]
//   2176 : float wty[256]
//   3200 : float wtw[256]
//   4224 : float wth[256]
//   5248 : int   wlabel[256]
//   6272 : int   zofs[768]
// bytes [0,96) zeroed by a 96-B hipMemsetAsync (poisoned-ws safe).

__device__ __forceinline__ void load_tile(const float* __restrict__ x,
                                          int dtile, int t, float4 (&v)[9]) {
    int chunk = dtile % 26, ba = dtile / 26;
    const float4* x4 = (const float4*)x + (size_t)ba * (CH * HWF4)
                                        + chunk * TF4;
    #pragma unroll
    for (int i = 0; i < 9; i++) {
        int idx = t + i * 256;
        if (idx < NF4) {
            int c = idx / TF4, q = idx - c * TF4;
            v[i] = x4[c * HWF4 + q];
        }
    }
}

__device__ __forceinline__ void finalize_total(float* acc, int* cnts,
                                               float* out_total) {
    float a0 = atomicAdd(&acc[0], 0.0f);   // coherent reads
    float a1 = atomicAdd(&acc[1], 0.0f);
    float a2 = atomicAdd(&acc[2], 0.0f);
    float a3 = atomicAdd(&acc[3], 0.0f);
    float wc = (float)atomicAdd(&cnts[0], 0);
    float zc = (float)atomicAdd(&cnts[1], 0);
    float n_obj = fmaxf(wc, 1.0f);
    float n_noobj = fmaxf((float)NCELLS - zc, 1.0f);
    float cls_den = fmaxf(80.0f * wc, 1.0f);
    out_total[0] = a1 / n_obj + a2 / cls_den + 0.5f * ((a0 - a3) / n_noobj);
}

__global__ __launch_bounds__(256) void yolo_one(
        const float* __restrict__ x, float* __restrict__ out,
        const float* __restrict__ target, float* acc, int* cnts,
        int* wofs, float* wtx, float* wty, float* wtw, float* wth,
        int* wlabel, int* zofs, float* __restrict__ out_total) {
    __shared__ float lds[LDSW];        // prep block aliases it (17.3 KB)
    __shared__ float red[4];
    __shared__ int s_nt[2];            // ping-pong next-tile broadcast
    __shared__ int s_flag[2];
    int bid = blockIdx.x;
    int t = threadIdx.x;

    if (bid == 0) {
        // ---------------- prep block (R11-verified) ----------------
        unsigned int* bm = (unsigned int*)lds;          // [NBMW]
        int* s_keyobj = (int*)lds + NBMW;               // [256]
        int* s_cnt = (int*)lds + NBMW + NT;             // {wcnt, zcnt}
        if (t == 0) { s_cnt[0] = 0; s_cnt[1] = 0; }
        for (int i = t; i < NBMW; i += 256) bm[i] = 0u;

        const float awc[3] = {10.f, 16.f, 33.f};
        const float ahc[3] = {13.f, 30.f, 23.f};
        float timg = target[t*6 + 0];
        float gxc  = target[t*6 + 1] * (float)WW;
        float gyc  = target[t*6 + 2] * (float)HH;
        float gw   = target[t*6 + 3] * (float)WW;
        float gh   = target[t*6 + 4] * (float)HH;
        int label  = (int)target[t*6 + 5];

        float best_iou = -1.0f;
        int best = 0, ignbits = 0;
        for (int a = 0; a < 3; a++) {
            float inter = fminf(awc[a], gw) * fminf(ahc[a], gh);
            float iou = inter / (awc[a]*ahc[a] + 1e-16f + gw*gh - inter);
            if (iou > best_iou) { best_iou = iou; best = a; }  // first-max
            if (iou > IGN_THR) ignbits |= (1 << a);
        }
        int img = (int)timg;
        int gi = (int)gxc, gj = (int)gyc;
        int pixel = gj * WW + gi;
        int cellbase = img * (NA * HW) + pixel;
        int keyobj = cellbase + best * HW;
        s_keyobj[t] = keyobj;
        __syncthreads();

        // winner iff no later target maps to same cell (fixed-trip scan)
        bool dup = false;
        #pragma unroll 8
        for (int m = 0; m < NT; m++) {
            int k = s_keyobj[m];
            dup = dup || (m > t && k == keyobj);
        }
        int sink = 0;
        if (!dup) {
            int p = atomicAdd(&s_cnt[0], 1);
            // publish winner table via device-coherent atomics (no fence)
            sink ^= atomicExch(&wofs[p], (img * NA + best) * (CH * HW) + pixel);
            sink ^= __float_as_int(atomicExch(&wtx[p], gxc - floorf(gxc)));
            sink ^= __float_as_int(atomicExch(&wty[p], gyc - floorf(gyc)));
            sink ^= __float_as_int(atomicExch(&wtw[p], logf(gw / awc[best] + 1e-16f)));
            sink ^= __float_as_int(atomicExch(&wth[p], logf(gh / ahc[best] + 1e-16f)));
            sink ^= atomicExch(&wlabel[p], label);
        }
        // distinct zeroed-noobj cells via bitmap (first setter appends)
        for (int a = 0; a < 3; a++) {
            bool flag = (a == best) || ((ignbits >> a) & 1);
            if (flag) {
                int key = cellbase + a * HW;
                unsigned int bit = 1u << (key & 31);
                unsigned int old = atomicOr(&bm[key >> 5], bit);
                if (!(old & bit)) {
                    int p = atomicAdd(&s_cnt[1], 1);
                    sink ^= atomicExch(&zofs[p],
                                ((img * NA + a) * CH + 4) * HW + pixel);
                }
            }
        }
        asm volatile("" :: "v"(sink) : "memory");  // table exchanges done
        __syncthreads();
        if (t == 0) {
            int o0 = atomicExch(&cnts[0], s_cnt[0]);
            int o1 = atomicExch(&cnts[1], s_cnt[1]);
            asm volatile("" :: "v"(o0), "v"(o1) : "memory");
            int of = atomicExch(&cnts[4], 1);      // publish: prep ready
            asm volatile("" :: "v"(of) : "memory");
            int o = atomicAdd(&cnts[3], 1);
            if (o == GRID - 1) finalize_total(acc, cnts, out_total);
        }
        return;
    }

    // ============ dense: work-stealing, raw-barrier pipelined ============
    int d = bid - 1;                    // 0..511
    const float awc[3] = {10.f, 16.f, 33.f};
    const float ahc[3] = {13.f, 30.f, 23.f};

    if (t == 0) s_nt[0] = atomicAdd(&cnts[5], 1);
    __syncthreads();
    int cur = s_nt[0];
    int par = 0;
    float4 v[9], vn[9];
    if (cur < NDENSE) load_tile(x, cur, t, v);
    int until_tail = (d < NEPI) ? 1 : -1;
    float noobj = 0.0f;

    while (cur < NDENSE) {
        if (t == 0) s_nt[par ^ 1] = atomicAdd(&cnts[5], 1);
        // ---- phase 1: transform v -> swizzled LDS ----
        int chunk = cur % 26;
        int ba    = cur / 26;
        int a     = ba % NA;
        #pragma unroll
        for (int i = 0; i < 9; i++) {
            int idx = t + i * 256;
            if (idx < NF4) {
                int c = idx / TF4, q = idx - c * TF4;
                float r[4] = {v[i].x, v[i].y, v[i].z, v[i].w};
                #pragma unroll
                for (int k = 0; k < 4; k++) {
                    int l = q * 4 + k;               // local pixel 0..103
                    float z = r[k], o;
                    if (c == 0) {
                        int wc = l - ((l >= WW) ? WW : 0);
                        o = (sigm(z) + (float)wc) * STRIDE_F;
                    } else if (c == 1) {
                        int hc = chunk * 2 + ((l >= WW) ? 1 : 0);
                        o = (sigm(z) + (float)hc) * STRIDE_F;
                    } else if (c == 2) {
                        o = expf(z) * awc[a];
                    } else if (c == 3) {
                        o = expf(z) * ahc[a];
                    } else {
                        o = sigm(z);
                        if (c == 4) noobj += splus(z);
                    }
                    lds[SW(c, l)] = o;
                }
            }
        }
        // ---- barrier A: LDS writes visible; vmcnt NOT drained ----
        asm volatile("s_waitcnt lgkmcnt(0)" ::: "memory");
        __builtin_amdgcn_s_barrier();
        __builtin_amdgcn_sched_barrier(0);

        // ---- prefetch next tile: loads stay in flight through phase 2 ----
        int nt = s_nt[par ^ 1];
        if (nt < NDENSE) load_tile(x, nt, t, vn);

        // ---- phase 2: LDS -> [cell][channel] float4 stores ----
        float4* o4 = (float4*)out + (size_t)ba * (HW * CH / 4) + chunk * NF4;
        #pragma unroll
        for (int i = 0; i < 9; i++) {
            int j = t + i * 256;
            if (j < NF4) {
                int flat = 4 * j;
                int cell = flat / CH;            // local cell 0..103
                int ch = flat - cell * CH;
                float4 w;
                float* pw = &w.x;
                #pragma unroll
                for (int k = 0; k < 4; k++) {
                    int chk = ch + k, cek = cell;
                    if (chk >= CH) { chk -= CH; cek += 1; }
                    pw[k] = lds[SW(chk, cek)];
                }
                o4[j] = w;
            }
        }
        // ---- barrier B: LDS reuse guard; prefetch loads remain in flight --
        asm volatile("s_waitcnt lgkmcnt(0)" ::: "memory");
        __builtin_amdgcn_s_barrier();
        __builtin_amdgcn_sched_barrier(0);

        #pragma unroll
        for (int i = 0; i < 9; i++) v[i] = vn[i];
        cur = nt;
        par ^= 1;

        // ---- tail epilogue for blocks 1..67 after their first tile ----
        if (until_tail > 0 && --until_tail == 0) {
            if (t == 0) {
                while (atomicAdd(&cnts[4], 0) == 0)     // prep long done
                    __builtin_amdgcn_s_sleep(8);
                s_flag[0] = atomicAdd(&cnts[0], 0);     // wcount
                s_flag[1] = atomicAdd(&cnts[1], 0);     // zcount
            }
            __syncthreads();
            int wave = t >> 6, lane = t & 63;
            if (d < 64) {
                // ---- winner gather: one winner per 64-lane wave ----
                int w = d * 4 + wave;
                if (w < s_flag[0]) {
                    int ofs = 0, label = 0;
                    float ttx = 0.f, tty = 0.f, ttw = 0.f, tth = 0.f;
                    if (lane == 0) {                   // coherent table reads
                        ofs   = atomicAdd(&wofs[w], 0);
                        label = atomicAdd(&wlabel[w], 0);
                        ttx = atomicAdd(&wtx[w], 0.0f);
                        tty = atomicAdd(&wty[w], 0.0f);
                        ttw = atomicAdd(&wtw[w], 0.0f);
                        tth = atomicAdd(&wth[w], 0.0f);
                    }
                    ofs   = __shfl(ofs, 0, 64);
                    label = __shfl(label, 0, 64);
                    const float* xp = x + ofs;
                    float lcls;
                    {   // class channels 0..63
                        float z = xp[(size_t)(5 + lane) * HW];
                        lcls = (lane == label) ? splus(-z) : splus(z);
                    }
                    if (lane < 16) {                   // class channels 64..79
                        int c = 64 + lane;
                        float z = xp[(size_t)(5 + c) * HW];
                        lcls += (c == label) ? splus(-z) : splus(z);
                    }
                    float other = 0.0f;
                    if (lane == 0) {
                        float z0 = xp[0];
                        float z2 = xp[(size_t)2 * HW];
                        float z4 = xp[(size_t)4 * HW];
                        float cx = sigm(z0);
                        float dx = cx - ttx, dy = cx - tty;  // ref bug: cx for y
                        float dw = z2 - ttw, dh = z2 - tth;  // ref bug: pw for h
                        other = dx*dx + dy*dy + dw*dw + dh*dh + splus(-z4);
                    }
                    for (int off = 32; off > 0; off >>= 1)
                        lcls += __shfl_down(lcls, off, 64);
                    if (lane == 0) {
                        float o1 = atomicAdd(&acc[1], other);
                        float o2 = atomicAdd(&acc[2], lcls);
                        asm volatile("" :: "v"(o1), "v"(o2) : "memory");
                    }
                }
            } else {
                // ---- zero-cell noobj corrections (768 over 3 blocks) ----
                int idx = (d - 64) * 256 + t;
                float vv = 0.0f;
                if (idx < s_flag[1]) {
                    int z = atomicAdd(&zofs[idx], 0);      // coherent read
                    vv = splus(x[z]);
                }
                for (int off = 32; off > 0; off >>= 1)
                    vv += __shfl_down(vv, off, 64);
                if ((t & 63) == 0) {
                    float o3 = atomicAdd(&acc[3], vv);
                    asm volatile("" :: "v"(o3) : "memory");
                }
            }
            __syncthreads();    // tail acc atomics consumed; rejoin queue
        }
    }

    // ---- block noobj reduce -> one atomic; then done protocol ----
    for (int off = 32; off > 0; off >>= 1)
        noobj += __shfl_down(noobj, off, 64);
    if ((t & 63) == 0) red[t >> 6] = noobj;
    __syncthreads();
    if (t == 0) {
        float old = atomicAdd(&acc[0], red[0] + red[1] + red[2] + red[3]);
        asm volatile("" :: "v"(old) : "memory");   // add at device point
        int o = atomicAdd(&cnts[3], 1);
        if (o == GRID - 1) finalize_total(acc, cnts, out_total);
    }
}

// ---------------------------------------------------------------------------
extern "C" void kernel_launch(void* const* d_in, const int* in_sizes, int n_in,
                              void* d_out, int out_size, void* d_ws, size_t ws_size,
                              hipStream_t stream) {
    (void)in_sizes; (void)n_in; (void)out_size; (void)ws_size;
    const float* x      = (const float*)d_in[0];
    const float* target = (const float*)d_in[1];
    float* out = (float*)d_out;

    char* ws = (char*)d_ws;
    float* acc      = (float*)(ws + 0);
    int*   cnts     = (int*)  (ws + 64);
    int*   wofs     = (int*)  (ws + 128);
    float* wtx      = (float*)(ws + 1152);
    float* wty      = (float*)(ws + 2176);
    float* wtw      = (float*)(ws + 3200);
    float* wth      = (float*)(ws + 4224);
    int*   wlabel   = (int*)  (ws + 5248);
    int*   zofs     = (int*)  (ws + 6272);

    // zero acc[16] + cnts[8] incl. work queue (ws is poisoned per iter)
    hipMemsetAsync(ws, 0, 96, stream);
    yolo_one<<<GRID, 256, 0, stream>>>(
        x, out, target, acc, cnts, wofs, wtx, wty, wtw, wth, wlabel, zofs,
        out + (size_t)NB * NA * HW * CH);
}